// Round 14
// baseline (116.536 us; speedup 1.0000x reference)
//
#include <hip/hip_runtime.h>
#include <hip/hip_bf16.h>
#include <math.h>

// ---- problem constants ----
#define B_ROWS 512
#define D_K    512
#define C_CLS  100000

#define COS_M 0.8775825618903728f
#define SIN_M 0.479425538604203f
#define TH_C  (-0.8775825618903728f)    // cos(pi - m)
#define MM_C  0.2397127693021015f       // sin(pi - m) * m

#define LOG2E_S 92.33248261689366f      // 64 * log2(e)
#define M0      92.4f                   // fixed softmax bound: |cos|<=1 -> |L|<=92.33
#define LN2F    0.6931471805599453f

#define BN 64                           // classes per chunk
#define NCHUNK 1563                     // ceil(100000/64)
#define NSTRIP 256                      // col-strips

typedef __attribute__((ext_vector_type(4))) float f32x4;
typedef __attribute__((ext_vector_type(2))) long long i64x2;
typedef long long i64;

__device__ inline float fexp2(float x) {
#if __has_builtin(__builtin_amdgcn_exp2f)
    return __builtin_amdgcn_exp2f(x);
#else
    return exp2f(x);
#endif
}

// ---------------- kernel 0: row-normalize -> fp8 e4m3, kk-INTERLEAVED layout ------
// (used for x only now). Permuted per-row byte order: pos = ks*64 + hi*16 + kk*8 +
// inner for original k-byte = ks*64 + kk*32 + hi*8 + inner.
__global__ __launch_bounds__(256) void rownorm8p_kernel(const float* __restrict__ in,
                                                        uint2* __restrict__ out,
                                                        float* __restrict__ rnout,
                                                        int nvalid) {
    const int wid = threadIdx.x >> 6;
    const int lane = threadIdx.x & 63;
    const int r = blockIdx.x * 4 + wid;
    const int newg = ((lane >> 3) << 3) + ((lane & 3) << 1) + ((lane >> 2) & 1);
    if (r >= nvalid) {
        out[(size_t)r * 64 + newg] = make_uint2(0u, 0u);
        return;
    }
    const float* row = in + (size_t)r * D_K + lane * 8;
    float4 a = *(const float4*)row;
    float4 b = *(const float4*)(row + 4);
    float ss = a.x * a.x + a.y * a.y + a.z * a.z + a.w * a.w
             + b.x * b.x + b.y * b.y + b.z * b.z + b.w * b.w;
    ss += __shfl_xor(ss, 1);  ss += __shfl_xor(ss, 2);  ss += __shfl_xor(ss, 4);
    ss += __shfl_xor(ss, 8);  ss += __shfl_xor(ss, 16); ss += __shfl_xor(ss, 32);
    const float rn = 1.0f / sqrtf(ss);
    int u0 = __builtin_amdgcn_cvt_pk_fp8_f32(a.x * rn, a.y * rn, 0, false);
    u0     = __builtin_amdgcn_cvt_pk_fp8_f32(a.z * rn, a.w * rn, u0, true);
    int u1 = __builtin_amdgcn_cvt_pk_fp8_f32(b.x * rn, b.y * rn, 0, false);
    u1     = __builtin_amdgcn_cvt_pk_fp8_f32(b.z * rn, b.w * rn, u1, true);
    out[(size_t)r * 64 + newg] = make_uint2((unsigned)u0, (unsigned)u1);
    if (rnout != nullptr && lane == 0) rnout[r] = rn;
}

// ---------------- kernel 1: FUSED fp32-W strip GEMM (r13 skeleton) ----------------
// Per chunk of 64 classes x K=512: while computing chunk ci from LDS buf[ci&1],
// reg-stage chunk ci+1 (fp32 load -> raw fp8 quant + ss fold -> swizzled
// ds_write_b64 into buf[(ci+1)&1]).  ONE __syncthreads per chunk.  Row 1/|w|
// applied POST-dot inside exp2 via rnsh[2][64] (double-buffered).  A fp8 pinned
// in regs.  Grid 512 = 2 blocks/CU; XCD-paired rb twins share W via L2.
__global__ __launch_bounds__(256, 2) void gemm_fused8_kernel(
        const unsigned char* __restrict__ xnb8p,  // [512][512] fp8 norm, interleaved
        const float* __restrict__ w,              // [100000][512] fp32 raw
        float* __restrict__ partials) {           // [NSTRIP][512]
    const int t    = threadIdx.x;
    const int lane = t & 63;
    const int wid  = t >> 6;
    const int cl   = lane & 15;
    const int hi   = lane >> 4;
    const int swz  = (cl >> 1) & 3;

    // XCD-pair swizzle: both rowblocks of a strip on one XCD (bijective for 512).
    const int j    = blockIdx.x;
    const int xcd  = j & 7;
    const int slot = j >> 3;
    const int s    = xcd + 8 * (slot >> 1);  // col-strip 0..255
    const int rb   = slot & 1;               // rowblock
    const int ch0 = (s * NCHUNK) >> 8;
    const int ch1 = ((s + 1) * NCHUNK) >> 8;
    const int nch = ch1 - ch0;
    const int cbase = ch0 * BN;

    __shared__ char  smem[2 * 32768];
    __shared__ float rnsh[2][64];

    // ---- staging identity: thread t owns in-chunk row t>>2, k-quarter t&3 ----
    const int r_st = t >> 2;
    const int q    = t & 3;
    const int gq   = (q & 1) * 2;            // logical granule base (halves 0/1 -> +0/+1)
    const int sub  = (q >> 1) * 8;           // byte offset within 16B granule
    const int swr  = (r_st >> 1) & 3;        // write-side granule swizzle

    float4 pa0, pb0, pa1, pb1;               // two stage sets (half = 8 floats)
    float  ssv = 0.f;

    // LOADH: load half hh (= kslice hh>>1, half hh&1) of chunk ci_ into set se
#define LOADH(ci_, hh, se)                                                       \
    {                                                                            \
        int _r = cbase + (ci_) * 64 + r_st;                                      \
        _r = _r < C_CLS ? _r : C_CLS - 1;                                        \
        const float* _p =                                                        \
            w + (size_t)_r * 512 + ((hh) >> 1) * 64 + q * 16 + ((hh) & 1) * 8;   \
        pa##se = *(const float4*)_p;                                             \
        pb##se = *(const float4*)(_p + 4);                                       \
    }
    // CONVH: quantize set se (= half hh) to fp8, fold ss, swizzled write -> buf_
#define CONVH(hh, se, buf_)                                                      \
    {                                                                            \
        float4 _A = pa##se, _B = pb##se;                                         \
        ssv += _A.x * _A.x + _A.y * _A.y + _A.z * _A.z + _A.w * _A.w             \
             + _B.x * _B.x + _B.y * _B.y + _B.z * _B.z + _B.w * _B.w;            \
        int _u0 = __builtin_amdgcn_cvt_pk_fp8_f32(_A.x, _A.y, 0, false);         \
        _u0     = __builtin_amdgcn_cvt_pk_fp8_f32(_A.z, _A.w, _u0, true);        \
        int _u1 = __builtin_amdgcn_cvt_pk_fp8_f32(_B.x, _B.y, 0, false);         \
        _u1     = __builtin_amdgcn_cvt_pk_fp8_f32(_B.z, _B.w, _u1, true);        \
        const int _g = (gq + ((hh) & 1)) ^ swr;                                  \
        *(uint2*)(smem + (buf_) * 32768 + ((hh) >> 1) * 4096 + r_st * 64 +       \
                  _g * 16 + sub) = make_uint2((unsigned)_u0, (unsigned)_u1);     \
    }

    // ---- A: 64 rows/wave, full K, fp8 pinned in regs ----
    i64 a8[4][16];
#pragma unroll
    for (int m = 0; m < 4; ++m) {
        const unsigned char* ap =
            xnb8p + (size_t)(rb * 256 + wid * 64 + m * 16 + cl) * 512 + hi * 16;
#pragma unroll
        for (int k = 0; k < 8; ++k) {
            i64x2 qv = *(const i64x2*)(ap + k * 64);
            a8[m][k * 2]     = qv[0];
            a8[m][k * 2 + 1] = qv[1];
        }
    }
#pragma unroll
    for (int m = 0; m < 4; ++m)
#pragma unroll
        for (int i = 0; i < 16; ++i)
            asm volatile("" : "+v"(a8[m][i]));

    // ---- prologue: stage chunk 0 (pipelined load/convert) + rnsh[0] ----
    LOADH(0, 0, 0)
    LOADH(0, 1, 1)
#pragma unroll
    for (int hh = 2; hh < 16; hh += 2) {
        CONVH(hh - 2, 0, 0)
        LOADH(0, hh, 0)
        CONVH(hh - 1, 1, 0)
        LOADH(0, hh + 1, 1)
    }
    CONVH(14, 0, 0)
    CONVH(15, 1, 0)
    {
        float a = ssv;
        a += __shfl_xor(a, 1);
        a += __shfl_xor(a, 2);
        if (q == 0) {
            const int c = cbase + r_st;
            rnsh[0][r_st] = (c < C_CLS) ? (1.0f / sqrtf(a)) : 0.0f;
        }
        ssv = 0.f;
    }
    __syncthreads();

    float sums[16];
#pragma unroll
    for (int i = 0; i < 16; ++i) sums[i] = 0.f;

    for (int ci = 0; ci < nch; ++ci) {
        const bool stg  = (ci + 1) < nch;
        const int  pbuf = (ci + 1) & 1;

        f32x4 acc[4][4];
#pragma unroll
        for (int m = 0; m < 4; ++m)
#pragma unroll
            for (int n = 0; n < 4; ++n) acc[m][n] = (f32x4){0.f, 0.f, 0.f, 0.f};

        const char* sB = smem + (ci & 1) * 32768;
#pragma unroll
        for (int k = 0; k < 8; ++k) {
            // stage chunk ci+1: convert halves loaded last kstep, issue this kstep's
            if (stg) {
                if (k > 0) CONVH(2 * k - 2, 0, pbuf)
                LOADH(ci + 1, 2 * k, 0)
                if (k > 0) CONVH(2 * k - 1, 1, pbuf)
                LOADH(ci + 1, 2 * k + 1, 1)
            }
            // compute kstep k of chunk ci
            i64x2 b[4];
#pragma unroll
            for (int n = 0; n < 4; ++n)
                b[n] = *(const i64x2*)(sB + k * 4096 + (n * 16 + cl) * 64 +
                                       ((hi ^ swz) << 4));
#pragma unroll
            for (int m = 0; m < 4; ++m)
#pragma unroll
                for (int n = 0; n < 4; ++n)
                    acc[m][n] = __builtin_amdgcn_mfma_f32_16x16x32_fp8_fp8(
                        a8[m][k * 2], b[n][0], acc[m][n], 0, 0, 0);
#pragma unroll
            for (int m = 0; m < 4; ++m)
#pragma unroll
                for (int n = 0; n < 4; ++n)
                    acc[m][n] = __builtin_amdgcn_mfma_f32_16x16x32_fp8_fp8(
                        a8[m][k * 2 + 1], b[n][1], acc[m][n], 0, 0, 0);
        }
        // tail converts + next chunk's rnorm
        if (stg) {
            CONVH(14, 0, pbuf)
            CONVH(15, 1, pbuf)
            float a = ssv;
            a += __shfl_xor(a, 1);
            a += __shfl_xor(a, 2);
            if (q == 0) {
                const int c = cbase + (ci + 1) * 64 + r_st;
                rnsh[pbuf][r_st] = (c < C_CLS) ? (1.0f / sqrtf(a)) : 0.0f;
            }
            ssv = 0.f;
        }
        // fixed-M0 accumulation with post-dot row norm (pad rows: rn=0 -> 2^-92.4)
        {
            float rl[4];
#pragma unroll
            for (int n = 0; n < 4; ++n) rl[n] = rnsh[ci & 1][n * 16 + cl] * LOG2E_S;
#pragma unroll
            for (int m = 0; m < 4; ++m)
#pragma unroll
                for (int jj = 0; jj < 4; ++jj)
#pragma unroll
                    for (int n = 0; n < 4; ++n)
                        sums[m * 4 + jj] += fexp2(fmaf(acc[m][n][jj], rl[n], -M0));
        }
        __syncthreads();   // ci+1's LDS writes + rnsh visible; buf[ci&1] reads done
    }
#undef LOADH
#undef CONVH

    // ---- strip epilogue: reduce each tracked row across its 16 col-lanes ----
#pragma unroll
    for (int m = 0; m < 4; ++m)
#pragma unroll
        for (int jj = 0; jj < 4; ++jj) {
            float v = sums[m * 4 + jj];
            v += __shfl_xor(v, 1);
            v += __shfl_xor(v, 2);
            v += __shfl_xor(v, 4);
            v += __shfl_xor(v, 8);
            if (cl == 0) {
                const int r = rb * 256 + wid * 64 + m * 16 + hi * 4 + jj;
                partials[s * B_ROWS + r] = v;
            }
        }
}

// ---------------- kernel 2: target-class cosine (fp32 exact) ----------------
__global__ __launch_bounds__(256) void tdot_kernel(const float* __restrict__ x,
                                                   const float* __restrict__ w,
                                                   const int* __restrict__ tgt,
                                                   const float* __restrict__ xrn,
                                                   float* __restrict__ tdot) {
    const int wid = threadIdx.x >> 6;
    const int lane = threadIdx.x & 63;
    const int b = blockIdx.x * 4 + wid;
    const int tg = tgt[b];
    const float* xr = x + (size_t)b * D_K + lane * 8;
    const float* wr = w + (size_t)tg * D_K + lane * 8;
    float4 xa = *(const float4*)xr;
    float4 xb = *(const float4*)(xr + 4);
    float4 wa = *(const float4*)wr;
    float4 wb = *(const float4*)(wr + 4);
    float xw = xa.x * wa.x + xa.y * wa.y + xa.z * wa.z + xa.w * wa.w
             + xb.x * wb.x + xb.y * wb.y + xb.z * wb.z + xb.w * wb.w;
    float ww = wa.x * wa.x + wa.y * wa.y + wa.z * wa.z + wa.w * wa.w
             + wb.x * wb.x + wb.y * wb.y + wb.z * wb.z + wb.w * wb.w;
#pragma unroll
    for (int m = 1; m < 64; m <<= 1) {
        xw += __shfl_xor(xw, m);
        ww += __shfl_xor(ww, m);
    }
    if (lane == 0) tdot[b] = xw * xrn[b] / sqrtf(ww);
}

// ---------------- kernel 3: per-row loss (margin fixup) + mean ----------------
__global__ __launch_bounds__(512) void final_kernel(const float* __restrict__ partials,
                                                    const float* __restrict__ tdot,
                                                    float* __restrict__ out) {
    const int b = threadIdx.x;   // 512 threads = 8 waves
    float s2 = 0.f;
    for (int s = 0; s < NSTRIP; ++s) s2 += partials[s * B_ROWS + b];
    const float cst = tdot[b];
    float c2 = 1.0f - cst * cst;
    c2 = fminf(fmaxf(c2, 0.0f), 1.0f);
    const float sine = sqrtf(c2);
    float phi = cst * COS_M - sine * SIN_M;
    phi = (cst > TH_C) ? phi : (cst - MM_C);
    const float Lt = cst * LOG2E_S;
    const float Lp = phi * LOG2E_S;
    // swap plain-target term for margin term in the denominator
    s2 = s2 - fexp2(Lt - M0) + fexp2(Lp - M0);
    float loss = LN2F * (M0 + log2f(s2) - Lp);
    loss += __shfl_xor(loss, 1);  loss += __shfl_xor(loss, 2);
    loss += __shfl_xor(loss, 4);  loss += __shfl_xor(loss, 8);
    loss += __shfl_xor(loss, 16); loss += __shfl_xor(loss, 32);
    __shared__ float sW[8];
    if ((b & 63) == 0) sW[b >> 6] = loss;
    __syncthreads();
    if (b == 0) {
        float tot = 0.f;
#pragma unroll
        for (int wv = 0; wv < 8; ++wv) tot += sW[wv];
        out[0] = tot * (1.0f / (float)B_ROWS);
    }
}

extern "C" void kernel_launch(void* const* d_in, const int* in_sizes, int n_in,
                              void* d_out, int out_size, void* d_ws, size_t ws_size,
                              hipStream_t stream) {
    const float* x = (const float*)d_in[0];
    const float* w = (const float*)d_in[1];
    const int* tgt = (const int*)d_in[2];
    float* out = (float*)d_out;

    char* ws = (char*)d_ws;
    size_t off = 0;
    unsigned char* xnb8 = (unsigned char*)(ws + off);
    off += (size_t)B_ROWS * D_K;                       // 256 KB
    off = (off + 255) & ~(size_t)255;
    float* xrn = (float*)(ws + off);
    off += B_ROWS * 4;
    off = (off + 255) & ~(size_t)255;
    float* partials = (float*)(ws + off);
    off += (size_t)NSTRIP * B_ROWS * 4;                // 512 KB
    off = (off + 255) & ~(size_t)255;
    float* tdot = (float*)(ws + off);
    off += B_ROWS * 4;

    rownorm8p_kernel<<<B_ROWS / 4, 256, 0, stream>>>(x, (uint2*)xnb8, xrn, B_ROWS);
    tdot_kernel<<<B_ROWS / 4, 256, 0, stream>>>(x, w, tgt, xrn, tdot);
    gemm_fused8_kernel<<<NSTRIP * 2, 256, 0, stream>>>(xnb8, w, partials);
    final_kernel<<<1, 512, 0, stream>>>(partials, tdot, out);
}

// Round 15
// 97.990 us; speedup vs baseline: 1.1893x; 1.1893x over previous
//
#include <hip/hip_runtime.h>
#include <hip/hip_bf16.h>
#include <math.h>

// ---- problem constants ----
#define B_ROWS 512
#define D_K    512
#define C_CLS  100000
#define C_PAD  100032                   // NCHUNK*64 (pad rows = fp8 zeros)

#define COS_M 0.8775825618903728f
#define SIN_M 0.479425538604203f
#define TH_C  (-0.8775825618903728f)    // cos(pi - m)
#define MM_C  0.2397127693021015f       // sin(pi - m) * m

#define LOG2E_S 92.33248261689366f      // 64 * log2(e)
#define M0      92.4f                   // fixed softmax bound: |cos|<=1 -> |L|<=92.33
#define LN2F    0.6931471805599453f

#define BN 64                           // classes per chunk
#define NCHUNK 1563                     // ceil(100000/64)
#define NSTRIP 256                      // col-strips

typedef __attribute__((ext_vector_type(4))) float f32x4;
typedef __attribute__((ext_vector_type(2))) long long i64x2;
typedef long long i64;

__device__ inline float fexp2(float x) {
#if __has_builtin(__builtin_amdgcn_exp2f)
    return __builtin_amdgcn_exp2f(x);
#else
    return exp2f(x);
#endif
}
__device__ inline void gload16(const void* g, void* lds) {
    __builtin_amdgcn_global_load_lds(
        (const __attribute__((address_space(1))) unsigned int*)g,
        (__attribute__((address_space(3))) unsigned int*)lds, 16, 0, 0);
}
#define VMCNT8() asm volatile("s_waitcnt vmcnt(8)" ::: "memory")
#define RAWBAR() __builtin_amdgcn_s_barrier()
#define SCHED0() __builtin_amdgcn_sched_barrier(0)

// ---------------- kernel 0: row-normalize -> fp8 e4m3, kk-INTERLEAVED layout ------
// Permuted per-row byte order: pos = ks*64 + hi*16 + kk*8 + inner for original
// k-byte = ks*64 + kk*32 + hi*8 + inner.  A 16B read at row*512 + ks*64 + hi*16
// yields the (kk0,kk1) MFMA fragment pair for lane-group hi, contiguous.
__global__ __launch_bounds__(256) void rownorm8p_kernel(const float* __restrict__ in,
                                                        uint2* __restrict__ out,
                                                        float* __restrict__ rnout,
                                                        int nvalid) {
    const int wid = threadIdx.x >> 6;
    const int lane = threadIdx.x & 63;
    const int r = blockIdx.x * 4 + wid;
    const int newg = ((lane >> 3) << 3) + ((lane & 3) << 1) + ((lane >> 2) & 1);
    if (r >= nvalid) {
        out[(size_t)r * 64 + newg] = make_uint2(0u, 0u);
        return;
    }
    const float* row = in + (size_t)r * D_K + lane * 8;
    float4 a = *(const float4*)row;
    float4 b = *(const float4*)(row + 4);
    float ss = a.x * a.x + a.y * a.y + a.z * a.z + a.w * a.w
             + b.x * b.x + b.y * b.y + b.z * b.z + b.w * b.w;
    ss += __shfl_xor(ss, 1);  ss += __shfl_xor(ss, 2);  ss += __shfl_xor(ss, 4);
    ss += __shfl_xor(ss, 8);  ss += __shfl_xor(ss, 16); ss += __shfl_xor(ss, 32);
    const float rn = 1.0f / sqrtf(ss);
    int u0 = __builtin_amdgcn_cvt_pk_fp8_f32(a.x * rn, a.y * rn, 0, false);
    u0     = __builtin_amdgcn_cvt_pk_fp8_f32(a.z * rn, a.w * rn, u0, true);
    int u1 = __builtin_amdgcn_cvt_pk_fp8_f32(b.x * rn, b.y * rn, 0, false);
    u1     = __builtin_amdgcn_cvt_pk_fp8_f32(b.z * rn, b.w * rn, u1, true);
    out[(size_t)r * 64 + newg] = make_uint2((unsigned)u0, (unsigned)u1);
    if (rnout != nullptr && lane == 0) rnout[r] = rn;
}

// ---------------- kernel 1: fp8 strip GEMM, half-chunk ring-4, counted vmcnt -----
// 256 thr / 4 waves; wave owns 64 rows; A fp8 pinned in regs (a8[4][16]).
// Staging: half-chunk = 64 classes x 256 K = 16 KB, ring of 4 LDS buffers.
// Each half-iteration: issue stage(h+2) [4 gload_lds], wait vmcnt(8) (h's loads
// landed; h+1/h+2 stay in flight -- NEVER drained to 0), s_barrier, compute
// 4 ksteps.  Statically specialized per k-half (no runtime a8 indices).
// XCD-pair swizzle: both rowblocks of a strip share an XCD -> wn8p L2-shared.
__global__ __launch_bounds__(256, 2) void gemm_ring_kernel(
        const unsigned char* __restrict__ xnb8p,  // [512][512] fp8 norm, interleaved
        const unsigned char* __restrict__ wn8p,   // [C_PAD][512] fp8 norm, interleaved
        float* __restrict__ partials) {           // [NSTRIP][512]
    const int t    = threadIdx.x;
    const int lane = t & 63;
    const int wid  = t >> 6;
    const int cl   = lane & 15;
    const int hi   = lane >> 4;
    const int swz  = (cl >> 1) & 3;

    // XCD-pair mapping (512 blocks): xcd = j&7; pair index p = j>>3.
    const int j   = blockIdx.x;
    const int s   = (j & 7) * 32 + ((j >> 3) >> 1);   // col-strip 0..255
    const int rb  = (j >> 3) & 1;                     // rowblock
    const int ch0 = (s * NCHUNK) >> 8;
    const int ch1 = ((s + 1) * NCHUNK) >> 8;
    const int nch = ch1 - ch0;
    const int cbase = ch0 * BN;
    const int H   = nch * 2;                          // half-chunks

    __shared__ char smem[4 * 16384];                  // 64 KB ring

    // staging identity: thread t covers row t>>2 of each kslice, granule lane&3;
    // source granule pre-swizzled (involution, matches read-side ^swz).
    const int srow = t >> 2;
    const int sgl  = (lane & 3) ^ ((lane >> 3) & 3);

#define STAGEH(hsrc, bufi)                                                      \
    {                                                                           \
        const int _ci = (hsrc) >> 1, _kh = (hsrc) & 1;                          \
        const unsigned char* _b = wn8p +                                        \
            (size_t)(cbase + _ci * 64 + srow) * 512 + _kh * 256 + (sgl << 4);   \
        char* _d = smem + (bufi) * 16384 + wid * 1024;                          \
        _Pragma("unroll")                                                       \
        for (int _j = 0; _j < 4; ++_j)                                          \
            gload16(_b + _j * 64, _d + _j * 4096);                              \
    }

    // ---- A: 64 rows/wave, full K, fp8 pinned in regs (direct global loads) ----
    i64 a8[4][16];
#pragma unroll
    for (int m = 0; m < 4; ++m) {
        const unsigned char* ap =
            xnb8p + (size_t)(rb * 256 + wid * 64 + m * 16 + cl) * 512 + hi * 16;
#pragma unroll
        for (int k = 0; k < 8; ++k) {
            i64x2 q = *(const i64x2*)(ap + k * 64);
            a8[m][k * 2]     = q[0];
            a8[m][k * 2 + 1] = q[1];
        }
    }
#pragma unroll
    for (int m = 0; m < 4; ++m)
#pragma unroll
        for (int i = 0; i < 16; ++i)
            asm volatile("" : "+v"(a8[m][i]));   // forces vmcnt wait + pins A

    // ---- prologue: stage half-chunks 0,1 (8 loads outstanding) ----
    STAGEH(0, 0)
    STAGEH(1, 1)

    float sums[16];
#pragma unroll
    for (int i = 0; i < 16; ++i) sums[i] = 0.f;

    // COMPUTE_HALF: 4 ksteps from LDS buffer, KH is a compile-time k-half (0/1)
#define COMPUTE_HALF(bufbyte, KH)                                               \
    {                                                                           \
        const char* sB = smem + (bufbyte);                                      \
        _Pragma("unroll")                                                       \
        for (int k = 0; k < 4; ++k) {                                           \
            i64x2 bfr[4];                                                       \
            _Pragma("unroll")                                                   \
            for (int n = 0; n < 4; ++n)                                         \
                bfr[n] = *(const i64x2*)(sB + k * 4096 + (n * 16 + cl) * 64 +   \
                                         ((hi ^ swz) << 4));                    \
            _Pragma("unroll")                                                   \
            for (int m = 0; m < 4; ++m)                                         \
                _Pragma("unroll")                                               \
                for (int n = 0; n < 4; ++n)                                     \
                    acc[m][n] = __builtin_amdgcn_mfma_f32_16x16x32_fp8_fp8(     \
                        a8[m][((KH) * 4 + k) * 2], bfr[n][0], acc[m][n],        \
                        0, 0, 0);                                               \
            _Pragma("unroll")                                                   \
            for (int m = 0; m < 4; ++m)                                         \
                _Pragma("unroll")                                               \
                for (int n = 0; n < 4; ++n)                                     \
                    acc[m][n] = __builtin_amdgcn_mfma_f32_16x16x32_fp8_fp8(     \
                        a8[m][((KH) * 4 + k) * 2 + 1], bfr[n][1], acc[m][n],    \
                        0, 0, 0);                                               \
        }                                                                       \
    }

    for (int ci = 0; ci < nch; ++ci) {
        const int sbase = (ci & 1) << 1;        // buffers being computed: sbase, sbase+1
        const int dbase = sbase ^ 2;            // buffers being staged: dbase, dbase+1
        const int h0 = 2 * ci, h1 = h0 + 1;

        f32x4 acc[4][4];
#pragma unroll
        for (int m = 0; m < 4; ++m)
#pragma unroll
            for (int n = 0; n < 4; ++n) acc[m][n] = (f32x4){0.f, 0.f, 0.f, 0.f};

        // ---- half 0 ----
        {
            const int hs = (h0 + 2 < H) ? h0 + 2 : H - 1;   // dummy re-stage at tail
            STAGEH(hs, dbase)
        }
        SCHED0();
        VMCNT8();      // h0's 4 loads landed; h1/h0+2 remain in flight
        RAWBAR();
        COMPUTE_HALF(sbase * 16384, 0)

        // ---- half 1 ----
        {
            const int hs = (h1 + 2 < H) ? h1 + 2 : H - 1;
            STAGEH(hs, dbase + 1)
        }
        SCHED0();
        VMCNT8();
        RAWBAR();
        COMPUTE_HALF((sbase + 1) * 16384, 1)

        // ---- chunk epilogue: fixed-M0 accumulation (pad rows -> 2^-92.4 ~ 0) ----
#pragma unroll
        for (int m = 0; m < 4; ++m)
#pragma unroll
            for (int jj = 0; jj < 4; ++jj)
#pragma unroll
                for (int n = 0; n < 4; ++n)
                    sums[m * 4 + jj] += fexp2(fmaf(acc[m][n][jj], LOG2E_S, -M0));
    }
#undef STAGEH
#undef COMPUTE_HALF

    // ---- strip epilogue: reduce each tracked row across its 16 col-lanes ----
#pragma unroll
    for (int m = 0; m < 4; ++m)
#pragma unroll
        for (int jj = 0; jj < 4; ++jj) {
            float v = sums[m * 4 + jj];
            v += __shfl_xor(v, 1);
            v += __shfl_xor(v, 2);
            v += __shfl_xor(v, 4);
            v += __shfl_xor(v, 8);
            if (cl == 0) {
                const int r = rb * 256 + wid * 64 + m * 16 + hi * 4 + jj;
                partials[s * B_ROWS + r] = v;
            }
        }
}

// ---------------- kernel 2: target-class cosine (fp32 exact) ----------------
__global__ __launch_bounds__(256) void tdot_kernel(const float* __restrict__ x,
                                                   const float* __restrict__ w,
                                                   const int* __restrict__ tgt,
                                                   const float* __restrict__ xrn,
                                                   float* __restrict__ tdot) {
    const int wid = threadIdx.x >> 6;
    const int lane = threadIdx.x & 63;
    const int b = blockIdx.x * 4 + wid;
    const int tg = tgt[b];
    const float* xr = x + (size_t)b * D_K + lane * 8;
    const float* wr = w + (size_t)tg * D_K + lane * 8;
    float4 xa = *(const float4*)xr;
    float4 xb = *(const float4*)(xr + 4);
    float4 wa = *(const float4*)wr;
    float4 wb = *(const float4*)(wr + 4);
    float xw = xa.x * wa.x + xa.y * wa.y + xa.z * wa.z + xa.w * wa.w
             + xb.x * wb.x + xb.y * wb.y + xb.z * wb.z + xb.w * wb.w;
    float ww = wa.x * wa.x + wa.y * wa.y + wa.z * wa.z + wa.w * wa.w
             + wb.x * wb.x + wb.y * wb.y + wb.z * wb.z + wb.w * wb.w;
#pragma unroll
    for (int m = 1; m < 64; m <<= 1) {
        xw += __shfl_xor(xw, m);
        ww += __shfl_xor(ww, m);
    }
    if (lane == 0) tdot[b] = xw * xrn[b] / sqrtf(ww);
}

// ---------------- kernel 3: per-row loss (margin fixup) + mean ----------------
__global__ __launch_bounds__(512) void final_kernel(const float* __restrict__ partials,
                                                    const float* __restrict__ tdot,
                                                    float* __restrict__ out) {
    const int b = threadIdx.x;   // 512 threads = 8 waves
    float s2 = 0.f;
    for (int s = 0; s < NSTRIP; ++s) s2 += partials[s * B_ROWS + b];
    const float cst = tdot[b];
    float c2 = 1.0f - cst * cst;
    c2 = fminf(fmaxf(c2, 0.0f), 1.0f);
    const float sine = sqrtf(c2);
    float phi = cst * COS_M - sine * SIN_M;
    phi = (cst > TH_C) ? phi : (cst - MM_C);
    const float Lt = cst * LOG2E_S;
    const float Lp = phi * LOG2E_S;
    // swap plain-target term for margin term in the denominator
    s2 = s2 - fexp2(Lt - M0) + fexp2(Lp - M0);
    float loss = LN2F * (M0 + log2f(s2) - Lp);
    loss += __shfl_xor(loss, 1);  loss += __shfl_xor(loss, 2);
    loss += __shfl_xor(loss, 4);  loss += __shfl_xor(loss, 8);
    loss += __shfl_xor(loss, 16); loss += __shfl_xor(loss, 32);
    __shared__ float sW[8];
    if ((b & 63) == 0) sW[b >> 6] = loss;
    __syncthreads();
    if (b == 0) {
        float tot = 0.f;
#pragma unroll
        for (int wv = 0; wv < 8; ++wv) tot += sW[wv];
        out[0] = tot * (1.0f / (float)B_ROWS);
    }
}

extern "C" void kernel_launch(void* const* d_in, const int* in_sizes, int n_in,
                              void* d_out, int out_size, void* d_ws, size_t ws_size,
                              hipStream_t stream) {
    const float* x = (const float*)d_in[0];
    const float* w = (const float*)d_in[1];
    const int* tgt = (const int*)d_in[2];
    float* out = (float*)d_out;

    char* ws = (char*)d_ws;
    size_t off = 0;
    unsigned char* xnb8 = (unsigned char*)(ws + off);
    off += (size_t)B_ROWS * D_K;                       // 256 KB
    off = (off + 255) & ~(size_t)255;
    unsigned char* wn8 = (unsigned char*)(ws + off);
    off += (size_t)C_PAD * D_K;                        // 51.2 MB
    off = (off + 255) & ~(size_t)255;
    float* xrn = (float*)(ws + off);
    off += B_ROWS * 4;
    off = (off + 255) & ~(size_t)255;
    float* partials = (float*)(ws + off);
    off += (size_t)NSTRIP * B_ROWS * 4;                // 512 KB
    off = (off + 255) & ~(size_t)255;
    float* tdot = (float*)(ws + off);
    off += B_ROWS * 4;

    rownorm8p_kernel<<<B_ROWS / 4, 256, 0, stream>>>(x, (uint2*)xnb8, xrn, B_ROWS);
    rownorm8p_kernel<<<C_PAD / 4, 256, 0, stream>>>(w, (uint2*)wn8, nullptr, C_CLS);
    tdot_kernel<<<B_ROWS / 4, 256, 0, stream>>>(x, w, tgt, xrn, tdot);
    gemm_ring_kernel<<<NSTRIP * 2, 256, 0, stream>>>(xnb8, wn8, partials);
    final_kernel<<<1, 512, 0, stream>>>(partials, tdot, out);
}